// Round 8
// baseline (717.013 us; speedup 1.0000x reference)
//
#include <hip/hip_runtime.h>
#include <hip/hip_bf16.h>

#define N_NODES 100000
#define N_EDGES 3200000
#define NB      100
#define NPG     1000
#define EPG     32000    // edges per graph
#define DIN     128
#define DH      64
#define DE      32
#define NCLS    10
#define SCAN_BLOCKS 98   // ceil(100000/1024)

// XCD-affine swizzle: graph g lives on XCD g%8 (blockIdx%8 = dispatch
// round-robin), keeping each graph's working set in ONE XCD's 4MB L2.
// R3 evidence: agg FETCH 254->38 MB.
// Aggregation = node-per-wave PULL gather from L2 with float4 sub-wave reads
// (R7 structure; R5 LDS-pull and R6 LDS-push both regressed >4x).
// R7 fix: k_scatter was 170us @ 110MB writes (4.3x amplification from random
// 4B stores). Now only ssrc is stored (1 atomic + 1 store per edge); coef
// dinv[s]*dinv[d] is recomputed in agg: dinv[d] hoisted per wave, dinv[s] is
// a same-address broadcast load (single transaction per sub-wave) from a
// 4KB L1-resident slice.

// ---------------- CSR build (dst-sorted) ----------------

__global__ void k_hist(const int* __restrict__ dst, int* __restrict__ cnt) {
    int xcd = blockIdx.x & 7, slot = blockIdx.x >> 3;
    int gi = slot / 125, cb = slot - gi * 125;
    int g = xcd + 8 * gi;
    if (g >= NB) return;
    int i = g * EPG + cb * 256 + threadIdx.x;
    atomicAdd(&cnt[dst[i]], 1);
}

__global__ void k_dinv(const int* __restrict__ cnt, float* __restrict__ dinv) {
    int i = blockIdx.x * 256 + threadIdx.x;
    if (i < N_NODES) dinv[i] = rsqrtf((float)cnt[i] + 2.0f);
}

__global__ void k_scanA(const int* __restrict__ cnt, int* __restrict__ partials) {
    __shared__ int sm[256];
    int b = blockIdx.x, t = threadIdx.x;
    int base = b * 1024 + t * 4;
    int s = 0;
    for (int j = 0; j < 4; j++) {
        int idx = base + j;
        if (idx < N_NODES) s += cnt[idx];
    }
    sm[t] = s; __syncthreads();
    for (int off = 128; off > 0; off >>= 1) {
        if (t < off) sm[t] += sm[t + off];
        __syncthreads();
    }
    if (t == 0) partials[b] = sm[0];
}

__global__ void k_scanB(int* __restrict__ partials, int* __restrict__ rowptr) {
    if (threadIdx.x == 0 && blockIdx.x == 0) {
        int acc = 0;
        for (int i = 0; i < SCAN_BLOCKS; i++) {
            int v = partials[i]; partials[i] = acc; acc += v;
        }
        rowptr[N_NODES] = acc;  // == N_EDGES
    }
}

__global__ void k_scanC(const int* __restrict__ cnt, const int* __restrict__ partials,
                        int* __restrict__ rowptr) {
    __shared__ int sm[256];
    int b = blockIdx.x, t = threadIdx.x;
    int base = b * 1024 + t * 4;
    int v[4]; int s = 0;
    for (int j = 0; j < 4; j++) {
        int idx = base + j;
        v[j] = (idx < N_NODES) ? cnt[idx] : 0;
        s += v[j];
    }
    sm[t] = s; __syncthreads();
    for (int off = 1; off < 256; off <<= 1) {
        int x = 0;
        if (t >= off) x = sm[t - off];
        __syncthreads();
        sm[t] += x;
        __syncthreads();
    }
    int g = partials[b] + (sm[t] - s);
    for (int j = 0; j < 4; j++) {
        int idx = base + j;
        if (idx < N_NODES) { rowptr[idx] = g; g += v[j]; }
    }
}

// Scatter: ONLY the src index (no coef). 1 atomic + 1 random 4B store/edge.

__global__ void k_scatter(const int* __restrict__ src, const int* __restrict__ dst,
                          int* __restrict__ fill, int* __restrict__ ssrc) {
    int xcd = blockIdx.x & 7, slot = blockIdx.x >> 3;
    int gi = slot / 125, cb = slot - gi * 125;
    int g = xcd + 8 * gi;
    if (g >= NB) return;
    int i = g * EPG + cb * 256 + threadIdx.x;
    int s = src[i], d = dst[i];
    int pos = atomicAdd(&fill[d], 1);
    ssrc[pos] = s;
}

// ---------------- GEMM 1: h = x @ [W_a1 | W_x1]  (128 -> 128) ----------------

__global__ __launch_bounds__(256) void k_gemm1(const float* __restrict__ x,
                                               const float* __restrict__ Wa,
                                               const float* __restrict__ Wx,
                                               float* __restrict__ h) {
    __shared__ float xs[32][128];
    __shared__ float ws[32][128];
    int xcd = blockIdx.x & 7, slot = blockIdx.x >> 3;
    int g = xcd + 8 * (slot >> 5);
    int chunk = slot & 31;
    if (g >= NB) return;
    int row0 = g * NPG + chunk * 32;
    int t = threadIdx.x;
    for (int i = 0; i < 4; i++) {
        int idx = t + 256 * i;
        int r = idx >> 5, k4 = idx & 31;
        int rr = row0 + r; if (rr >= N_NODES) rr = N_NODES - 1;
        *(float4*)&xs[r][k4 * 4] = *(const float4*)&x[(size_t)rr * 128 + k4 * 4];
    }
    float acc[4][4] = {};
    int rg = t >> 5, cg = t & 31;
    for (int kt = 0; kt < 4; kt++) {
        __syncthreads();
        for (int i = 0; i < 4; i++) {
            int idx = t + 256 * i;
            int kk = idx >> 5, c4 = idx & 31;
            int k = kt * 32 + kk, c = c4 * 4;
            float4 v;
            if (c < 64) v = *(const float4*)&Wa[k * 64 + c];
            else        v = *(const float4*)&Wx[k * 64 + (c - 64)];
            *(float4*)&ws[kk][c] = v;
        }
        __syncthreads();
        for (int kk = 0; kk < 32; kk++) {
            float4 w = *(float4*)&ws[kk][cg * 4];
            float xv[4];
            for (int i = 0; i < 4; i++) xv[i] = xs[rg * 4 + i][kt * 32 + kk];
            for (int i = 0; i < 4; i++) {
                acc[i][0] += xv[i] * w.x; acc[i][1] += xv[i] * w.y;
                acc[i][2] += xv[i] * w.z; acc[i][3] += xv[i] * w.w;
            }
        }
    }
    for (int i = 0; i < 4; i++) {
        int r = row0 + rg * 4 + i;
        if (r < N_NODES)
            *(float4*)&h[(size_t)r * 128 + cg * 4] =
                make_float4(acc[i][0], acc[i][1], acc[i][2], acc[i][3]);
    }
}

// ---------------- Aggregation, 128 channels (layer 1) ----------------
// Wave = 1 node. Half-waves handle even/odd edges; float4 (4 ch) per lane;
// 16 edges in flight. dinv[s] broadcast-loaded; dinv[d] hoisted to epilogue.

__global__ __launch_bounds__(256) void k_agg128(const float* __restrict__ h,
                                                const int* __restrict__ rowptr,
                                                const int* __restrict__ ssrc,
                                                const float* __restrict__ dinv,
                                                const float* __restrict__ ba,
                                                const float* __restrict__ bx,
                                                float* __restrict__ outB) {
    int xcd = blockIdx.x & 7, slot = blockIdx.x >> 3;
    int gi = slot / 250, chunk = slot - gi * 250;
    int g = xcd + 8 * gi;
    if (g >= NB) return;
    int wid  = g * NPG + chunk * 4 + (threadIdx.x >> 6);
    int lane = threadIdx.x & 63;
    int sub = lane >> 5;           // 0: even edges, 1: odd edges
    int cl  = lane & 31;           // float4 channel group
    const float4* h4 = (const float4*)h;   // row stride = 32 float4
    float4 acc = make_float4(0.f, 0.f, 0.f, 0.f);
    int e0 = rowptr[wid], e1 = rowptr[wid + 1];
    int e = e0;
    for (; e + 16 <= e1; e += 16) {
        int s[8];
        #pragma unroll
        for (int j = 0; j < 8; j++) s[j] = ssrc[e + 2 * j + sub];
        float dv[8];
        #pragma unroll
        for (int j = 0; j < 8; j++) dv[j] = dinv[s[j]];   // broadcast (same addr across half-wave)
        float4 r[8];
        #pragma unroll
        for (int j = 0; j < 8; j++) r[j] = h4[(size_t)s[j] * 32 + cl];
        #pragma unroll
        for (int j = 0; j < 8; j++) {
            acc.x += dv[j] * r[j].x; acc.y += dv[j] * r[j].y;
            acc.z += dv[j] * r[j].z; acc.w += dv[j] * r[j].w;
        }
    }
    for (; e < e1; e += 2) {
        int ee = e + sub;
        int ss = ssrc[e]; float dv = 0.0f;
        if (ee < e1) { ss = ssrc[ee]; dv = dinv[ss]; }
        float4 r = h4[(size_t)ss * 32 + cl];
        acc.x += dv * r.x; acc.y += dv * r.y;
        acc.z += dv * r.z; acc.w += dv * r.w;
    }
    acc.x += __shfl_xor(acc.x, 32);
    acc.y += __shfl_xor(acc.y, 32);
    acc.z += __shfl_xor(acc.z, 32);
    acc.w += __shfl_xor(acc.w, 32);
    if (sub == 0) {
        float di = dinv[wid];
        float sw = 2.0f * di * di;
        float4 hv = h4[(size_t)wid * 32 + cl];
        int cb = cl * 4;                       // group fully in ba or bx (64%4==0)
        const float* bb = (cb < 64) ? &ba[cb] : &bx[cb - 64];
        acc.x = fmaxf(di * acc.x + sw * hv.x + bb[0], 0.0f);
        acc.y = fmaxf(di * acc.y + sw * hv.y + bb[1], 0.0f);
        acc.z = fmaxf(di * acc.z + sw * hv.z + bb[2], 0.0f);
        acc.w = fmaxf(di * acc.w + sw * hv.w + bb[3], 0.0f);
        ((float4*)outB)[(size_t)wid * 32 + cl] = acc;
    }
}

// ---------------- Aggregation, 64 channels (layer 2) ----------------
// Quarter-waves handle edge j%4; float4 per lane; 32 edges in flight.
// cg<32: a-branch (+b_a2, no relu); cg>=32: x-branch (+b_x2, relu).

__global__ __launch_bounds__(256) void k_agg64(const float* __restrict__ g2,
                                               const int* __restrict__ rowptr,
                                               const int* __restrict__ ssrc,
                                               const float* __restrict__ dinv,
                                               const float* __restrict__ ba2,
                                               const float* __restrict__ bx2,
                                               float* __restrict__ s2) {
    int xcd = blockIdx.x & 7, slot = blockIdx.x >> 3;
    int gi = slot / 250, chunk = slot - gi * 250;
    int g = xcd + 8 * gi;
    if (g >= NB) return;
    int wid  = g * NPG + chunk * 4 + (threadIdx.x >> 6);
    int lane = threadIdx.x & 63;
    int sub = lane >> 4;           // 0..3: edge j%4
    int cl  = lane & 15;           // float4 channel group
    const float4* g4 = (const float4*)g2;  // row stride = 16 float4
    float4 acc = make_float4(0.f, 0.f, 0.f, 0.f);
    int e0 = rowptr[wid], e1 = rowptr[wid + 1];
    int e = e0;
    for (; e + 32 <= e1; e += 32) {
        int s[8];
        #pragma unroll
        for (int j = 0; j < 8; j++) s[j] = ssrc[e + 4 * j + sub];
        float dv[8];
        #pragma unroll
        for (int j = 0; j < 8; j++) dv[j] = dinv[s[j]];
        float4 r[8];
        #pragma unroll
        for (int j = 0; j < 8; j++) r[j] = g4[(size_t)s[j] * 16 + cl];
        #pragma unroll
        for (int j = 0; j < 8; j++) {
            acc.x += dv[j] * r[j].x; acc.y += dv[j] * r[j].y;
            acc.z += dv[j] * r[j].z; acc.w += dv[j] * r[j].w;
        }
    }
    for (; e < e1; e += 4) {
        int ee = e + sub;
        int ss = ssrc[e]; float dv = 0.0f;
        if (ee < e1) { ss = ssrc[ee]; dv = dinv[ss]; }
        float4 r = g4[(size_t)ss * 16 + cl];
        acc.x += dv * r.x; acc.y += dv * r.y;
        acc.z += dv * r.z; acc.w += dv * r.w;
    }
    acc.x += __shfl_xor(acc.x, 16); acc.x += __shfl_xor(acc.x, 32);
    acc.y += __shfl_xor(acc.y, 16); acc.y += __shfl_xor(acc.y, 32);
    acc.z += __shfl_xor(acc.z, 16); acc.z += __shfl_xor(acc.z, 32);
    acc.w += __shfl_xor(acc.w, 16); acc.w += __shfl_xor(acc.w, 32);
    if (sub == 0) {
        float di = dinv[wid];
        float sw = 2.0f * di * di;
        float4 hv = g4[(size_t)wid * 16 + cl];
        int cb = cl * 4;                       // group fully in a or x (32%4==0)
        if (cb < 32) {
            acc.x = di * acc.x + sw * hv.x + ba2[cb + 0];
            acc.y = di * acc.y + sw * hv.y + ba2[cb + 1];
            acc.z = di * acc.z + sw * hv.z + ba2[cb + 2];
            acc.w = di * acc.w + sw * hv.w + ba2[cb + 3];
        } else {
            acc.x = fmaxf(di * acc.x + sw * hv.x + bx2[cb - 32 + 0], 0.0f);
            acc.y = fmaxf(di * acc.y + sw * hv.y + bx2[cb - 32 + 1], 0.0f);
            acc.z = fmaxf(di * acc.z + sw * hv.z + bx2[cb - 32 + 2], 0.0f);
            acc.w = fmaxf(di * acc.w + sw * hv.w + bx2[cb - 32 + 3], 0.0f);
        }
        ((float4*)s2)[(size_t)wid * 16 + cl] = acc;
    }
}

// ---------------- GEMM 2: g2 = [a1|x1] @ blockdiag(W_a2, W_x2) (64ch out) ----------------

__global__ __launch_bounds__(256) void k_gemm2(const float* __restrict__ Bm,
                                               const float* __restrict__ Wa2,
                                               const float* __restrict__ Wx2,
                                               float* __restrict__ g2) {
    __shared__ float xs[64][132];
    __shared__ float ws[64][68];
    int xcd = blockIdx.x & 7, slot = blockIdx.x >> 3;
    int g = xcd + 8 * (slot >> 4);
    int chunk = slot & 15;
    if (g >= NB) return;
    int row0 = g * NPG + chunk * 64;   // chunk 15 spills into next graph: benign dup
    int t = threadIdx.x;
    for (int i = 0; i < 4; i++) {
        int idx = t + 256 * i;
        int k = idx >> 4, c4 = idx & 15, c = c4 * 4;
        float4 v;
        if (c < 32) v = *(const float4*)&Wa2[k * 32 + c];
        else        v = *(const float4*)&Wx2[k * 32 + (c - 32)];
        *(float4*)&ws[k][c] = v;
    }
    for (int i = 0; i < 8; i++) {
        int idx = t + 256 * i;
        int r = idx >> 5, k4 = idx & 31;
        int rr = row0 + r; if (rr >= N_NODES) rr = N_NODES - 1;
        *(float4*)&xs[r][k4 * 4] = *(const float4*)&Bm[(size_t)rr * 128 + k4 * 4];
    }
    __syncthreads();
    int cg = t & 15, rg = t >> 4;
    int koff = (cg < 8) ? 0 : 64;
    float acc[4][4] = {};
    for (int k = 0; k < 64; k++) {
        float4 w = *(float4*)&ws[k][cg * 4];
        float xv[4];
        for (int i = 0; i < 4; i++) xv[i] = xs[rg * 4 + i][koff + k];
        for (int i = 0; i < 4; i++) {
            acc[i][0] += xv[i] * w.x; acc[i][1] += xv[i] * w.y;
            acc[i][2] += xv[i] * w.z; acc[i][3] += xv[i] * w.w;
        }
    }
    for (int i = 0; i < 4; i++) {
        int r = row0 + rg * 4 + i;
        if (r < N_NODES)
            *(float4*)&g2[(size_t)r * 64 + cg * 4] =
                make_float4(acc[i][0], acc[i][1], acc[i][2], acc[i][3]);
    }
}

// ---------------- Segment softmax stats (cols 0..31), per graph ----------------

__global__ __launch_bounds__(256) void k_smax(const float* __restrict__ s2,
                                              float* __restrict__ gmax,
                                              float* __restrict__ sinv) {
    __shared__ float red[8][32];
    int g = (blockIdx.x & 7) + 8 * (blockIdx.x >> 3);
    if (g >= NB) return;
    int t = threadIdx.x;
    int c = t & 31, sub = t >> 5;
    size_t base = (size_t)g * NPG;
    float m = -1e30f;
    for (int n = sub; n < NPG; n += 8)
        m = fmaxf(m, s2[(base + n) * 64 + c]);
    red[sub][c] = m; __syncthreads();
    if (sub == 0) {
        for (int j = 1; j < 8; j++) m = fmaxf(m, red[j][c]);
        red[0][c] = m;
        gmax[g * 32 + c] = m;
    }
    __syncthreads();
    m = red[0][c];
    __syncthreads();
    float sum = 0.0f;
    for (int n = sub; n < NPG; n += 8)
        sum += expf(s2[(base + n) * 64 + c] - m);
    red[sub][c] = sum; __syncthreads();
    if (sub == 0) {
        for (int j = 1; j < 8; j++) sum += red[j][c];
        sinv[g * 32 + c] = 1.0f / sum;
    }
}

// ---------------- Bilinear pool (spill-free; exp at staging) ----------------
// Direct per-chunk partial stores: prods[(g*4+ch)][1024]; no atomics/memset.

__global__ __launch_bounds__(256) void k_pool(const float* __restrict__ s2,
                                              const float* __restrict__ gmax,
                                              float* __restrict__ prods) {
    __shared__ float ta[50][32];
    __shared__ float tx[50][32];
    __shared__ float gm[32];
    int xcd = blockIdx.x & 7, slot = blockIdx.x >> 3;
    int g = xcd + 8 * (slot >> 2);
    int ch = slot & 3;
    if (g >= NB) return;
    int t = threadIdx.x;
    if (t < 32) gm[t] = gmax[g * 32 + t];
    int e  = t >> 3;
    int f4 = t & 7;
    float a0 = 0.f, a1 = 0.f, a2 = 0.f, a3 = 0.f;
    int base = g * NPG + ch * 250;
    for (int n0 = 0; n0 < 250; n0 += 50) {
        __syncthreads();
        for (int i = t; i < 50 * 16; i += 256) {
            int r = i >> 4, c4 = i & 15;
            float4 v = *(const float4*)&s2[(size_t)(base + n0 + r) * 64 + c4 * 4];
            if (c4 < 8) {
                int cb = c4 * 4;
                v.x = __expf(v.x - gm[cb + 0]);
                v.y = __expf(v.y - gm[cb + 1]);
                v.z = __expf(v.z - gm[cb + 2]);
                v.w = __expf(v.w - gm[cb + 3]);
                *(float4*)&ta[r][cb] = v;
            } else {
                *(float4*)&tx[r][(c4 - 8) * 4] = v;
            }
        }
        __syncthreads();
        #pragma unroll 5
        for (int n = 0; n < 50; n++) {
            float a   = ta[n][e];
            float4 xv = *(float4*)&tx[n][f4 * 4];
            a0 += a * xv.x; a1 += a * xv.y; a2 += a * xv.z; a3 += a * xv.w;
        }
    }
    *(float4*)&prods[((size_t)(g * 4 + ch)) * 1024 + e * 32 + f4 * 4] =
        make_float4(a0, a1, a2, a3);
}

// ---------------- Head: sum 4 chunk-partials, linear, softmax ----------------

__global__ __launch_bounds__(256) void k_head(const float* __restrict__ prods,
                                              const float* __restrict__ sinv,
                                              const float* __restrict__ Wlin,
                                              const float* __restrict__ blin,
                                              float* __restrict__ out) {
    __shared__ float red[4][NCLS];
    int g = (blockIdx.x & 7) + 8 * (blockIdx.x >> 3);
    if (g >= NB) return;
    int t = threadIdx.x;
    float p[NCLS];
    for (int c = 0; c < NCLS; c++) p[c] = 0.0f;
    const float* pg = &prods[(size_t)g * 4 * 1024];
    for (int j = 0; j < 4; j++) {
        int k = t * 4 + j;
        int e = k >> 5;
        float v = (pg[k] + pg[1024 + k] + pg[2048 + k] + pg[3072 + k]) * sinv[g * 32 + e];
        const float* wrow = &Wlin[(size_t)k * NCLS];
        for (int c = 0; c < NCLS; c++) p[c] += v * wrow[c];
    }
    for (int off = 32; off > 0; off >>= 1)
        for (int c = 0; c < NCLS; c++) p[c] += __shfl_down(p[c], off, 64);
    int wave = t >> 6, lane = t & 63;
    if (lane == 0)
        for (int c = 0; c < NCLS; c++) red[wave][c] = p[c];
    __syncthreads();
    if (t == 0) {
        float logits[NCLS]; float mx = -1e30f;
        for (int c = 0; c < NCLS; c++) {
            logits[c] = red[0][c] + red[1][c] + red[2][c] + red[3][c] + blin[c];
            mx = fmaxf(mx, logits[c]);
        }
        float s = 0.0f;
        for (int c = 0; c < NCLS; c++) { logits[c] = expf(logits[c] - mx); s += logits[c]; }
        float inv = 1.0f / s;
        for (int c = 0; c < NCLS; c++) out[g * NCLS + c] = logits[c] * inv;
    }
}

// ---------------- launch ----------------

extern "C" void kernel_launch(void* const* d_in, const int* in_sizes, int n_in,
                              void* d_out, int out_size, void* d_ws, size_t ws_size,
                              hipStream_t stream) {
    const float* x    = (const float*)d_in[0];
    const int*   ei   = (const int*)d_in[1];
    const float* Wa1  = (const float*)d_in[3];
    const float* ba1  = (const float*)d_in[4];
    const float* Wa2  = (const float*)d_in[5];
    const float* ba2  = (const float*)d_in[6];
    const float* Wx1  = (const float*)d_in[7];
    const float* bx1  = (const float*)d_in[8];
    const float* Wx2  = (const float*)d_in[9];
    const float* bx2  = (const float*)d_in[10];
    const float* Wlin = (const float*)d_in[11];
    const float* blin = (const float*)d_in[12];
    float* out = (float*)d_out;

    char* w = (char*)d_ws;
    auto alloc = [&](size_t bytes) -> void* {
        void* p = (void*)w;
        w += (bytes + 255) & ~(size_t)255;
        return p;
    };
    int*   cnt      = (int*)alloc((N_NODES + 1) * sizeof(int));
    int*   rowptr   = (int*)alloc((N_NODES + 1) * sizeof(int));
    int*   fill     = (int*)alloc(N_NODES * sizeof(int));
    float* dinv     = (float*)alloc(N_NODES * sizeof(float));
    int*   partials = (int*)alloc(1024);
    int*   ssrc     = (int*)alloc((size_t)N_EDGES * sizeof(int));
    float* gmax     = (float*)alloc(NB * DE * sizeof(float));
    float* sinv     = (float*)alloc(NB * DE * sizeof(float));
    float* prods    = (float*)alloc((size_t)NB * 4 * 1024 * sizeof(float));
    float* bufA     = (float*)alloc((size_t)N_NODES * 128 * sizeof(float));
    float* bufB     = (float*)alloc((size_t)N_NODES * 128 * sizeof(float));

    const int* srcp = ei;
    const int* dstp = ei + N_EDGES;

    hipMemsetAsync(cnt, 0, (N_NODES + 1) * sizeof(int), stream);
    k_hist<<<8 * 13 * 125, 256, 0, stream>>>(dstp, cnt);
    k_dinv<<<(N_NODES + 255) / 256, 256, 0, stream>>>(cnt, dinv);
    k_scanA<<<SCAN_BLOCKS, 256, 0, stream>>>(cnt, partials);
    k_scanB<<<1, 64, 0, stream>>>(partials, rowptr);
    k_scanC<<<SCAN_BLOCKS, 256, 0, stream>>>(cnt, partials, rowptr);
    hipMemcpyAsync(fill, rowptr, N_NODES * sizeof(int), hipMemcpyDeviceToDevice, stream);
    k_scatter<<<8 * 13 * 125, 256, 0, stream>>>(srcp, dstp, fill, ssrc);

    k_gemm1<<<8 * 13 * 32, 256, 0, stream>>>(x, Wa1, Wx1, bufA);
    k_agg128<<<8 * 13 * 250, 256, 0, stream>>>(bufA, rowptr, ssrc, dinv, ba1, bx1, bufB);
    k_gemm2<<<8 * 13 * 16, 256, 0, stream>>>(bufB, Wa2, Wx2, bufA);
    k_agg64<<<8 * 13 * 250, 256, 0, stream>>>(bufA, rowptr, ssrc, dinv, ba2, bx2, bufB);
    k_smax<<<8 * 13, 256, 0, stream>>>(bufB, gmax, sinv);
    k_pool<<<8 * 13 * 4, 256, 0, stream>>>(bufB, gmax, prods);
    k_head<<<8 * 13, 256, 0, stream>>>(prods, sinv, Wlin, blin, out);
}

// Round 9
// 506.309 us; speedup vs baseline: 1.4162x; 1.4162x over previous
//
#include <hip/hip_runtime.h>
#include <hip/hip_bf16.h>

#define N_NODES 100000
#define N_EDGES 3200000
#define NB      100
#define NPG     1000
#define EPG     32000    // edges per graph
#define DIN     128
#define DH      64
#define DE      32
#define NCLS    10

// XCD-affine swizzle: graph g lives on XCD g%8 (blockIdx%8 = dispatch
// round-robin), keeping each graph's working set in ONE XCD's 4MB L2.
// R3 evidence: agg FETCH 254->38 MB.
// Aggregation = node-per-wave PULL gather from L2 with float4 sub-wave reads
// (R7 structure; R5 LDS-pull and R6 LDS-push both regressed >4x).
// R8 evidence: global-atomic scatter is transaction-bound (147us, 96MB writes
// for 12.8MB payload). R9: per-graph LDS counting sort -- histogram, scan,
// scatter all in LDS; ushort(local idx) edge list written out coalesced.

// ---------------- Per-graph CSR build, entirely in LDS ----------------
// One block per graph. Produces rowptr (global edge offsets), dinv, and
// the dst-sorted ushort src-index list. Zero global atomics.

__global__ __launch_bounds__(256) void k_sort(const int* __restrict__ src,
                                              const int* __restrict__ dst,
                                              int* __restrict__ rowptr,
                                              float* __restrict__ dinv,
                                              unsigned short* __restrict__ ssrc) {
    __shared__ __align__(16) unsigned short buf[EPG];  // 64 KB sorted output
    __shared__ int cnt[NPG];                            // histogram
    __shared__ int pre[NPG];                            // exclusive prefix -> fill
    __shared__ int sm[256];
    int g = (blockIdx.x & 7) + 8 * (blockIdx.x >> 3);
    if (g >= NB) return;
    int t = threadIdx.x;
    int ebase = g * EPG, nbase = g * NPG;
    for (int i = t; i < NPG; i += 256) cnt[i] = 0;
    __syncthreads();
    for (int i = t; i < EPG; i += 256)
        atomicAdd(&cnt[dst[ebase + i] - nbase], 1);
    __syncthreads();
    for (int i = t; i < NPG; i += 256)
        dinv[nbase + i] = rsqrtf((float)cnt[i] + 2.0f);
    // block-wide exclusive scan of cnt[0..999] (250 threads x 4 elements)
    int v0 = 0, v1 = 0, v2 = 0, v3 = 0, tot = 0;
    if (t < 250) {
        v0 = cnt[4 * t]; v1 = cnt[4 * t + 1];
        v2 = cnt[4 * t + 2]; v3 = cnt[4 * t + 3];
        tot = v0 + v1 + v2 + v3;
    }
    sm[t] = tot;
    __syncthreads();
    for (int off = 1; off < 256; off <<= 1) {
        int x = (t >= off) ? sm[t - off] : 0;
        __syncthreads();
        sm[t] += x;
        __syncthreads();
    }
    if (t < 250) {
        int ex = sm[t] - tot;          // exclusive prefix of this thread's chunk
        pre[4 * t]     = ex;
        pre[4 * t + 1] = ex + v0;
        pre[4 * t + 2] = ex + v0 + v1;
        pre[4 * t + 3] = ex + v0 + v1 + v2;
    }
    __syncthreads();
    for (int i = t; i < NPG; i += 256)
        rowptr[nbase + i] = ebase + pre[i];
    if (g == NB - 1 && t == 0) rowptr[N_NODES] = N_EDGES;
    __syncthreads();
    // scatter into LDS (pre[] doubles as fill counters)
    for (int i = t; i < EPG; i += 256) {
        int e = ebase + i;
        int d = dst[e] - nbase;
        int s = src[e] - nbase;
        int pos = atomicAdd(&pre[d], 1);
        buf[pos] = (unsigned short)s;
    }
    __syncthreads();
    // coalesced 16B/lane writeout
    uint4* gout = (uint4*)(ssrc + ebase);
    const uint4* lbuf = (const uint4*)buf;
    for (int i = t; i < EPG / 8; i += 256)   // 4000 x 16B
        gout[i] = lbuf[i];
}

// ---------------- GEMM 1: h = x @ [W_a1 | W_x1]  (128 -> 128) ----------------

__global__ __launch_bounds__(256) void k_gemm1(const float* __restrict__ x,
                                               const float* __restrict__ Wa,
                                               const float* __restrict__ Wx,
                                               float* __restrict__ h) {
    __shared__ float xs[32][128];
    __shared__ float ws[32][128];
    int xcd = blockIdx.x & 7, slot = blockIdx.x >> 3;
    int g = xcd + 8 * (slot >> 5);
    int chunk = slot & 31;
    if (g >= NB) return;
    int row0 = g * NPG + chunk * 32;
    int t = threadIdx.x;
    for (int i = 0; i < 4; i++) {
        int idx = t + 256 * i;
        int r = idx >> 5, k4 = idx & 31;
        int rr = row0 + r; if (rr >= N_NODES) rr = N_NODES - 1;
        *(float4*)&xs[r][k4 * 4] = *(const float4*)&x[(size_t)rr * 128 + k4 * 4];
    }
    float acc[4][4] = {};
    int rg = t >> 5, cg = t & 31;
    for (int kt = 0; kt < 4; kt++) {
        __syncthreads();
        for (int i = 0; i < 4; i++) {
            int idx = t + 256 * i;
            int kk = idx >> 5, c4 = idx & 31;
            int k = kt * 32 + kk, c = c4 * 4;
            float4 v;
            if (c < 64) v = *(const float4*)&Wa[k * 64 + c];
            else        v = *(const float4*)&Wx[k * 64 + (c - 64)];
            *(float4*)&ws[kk][c] = v;
        }
        __syncthreads();
        for (int kk = 0; kk < 32; kk++) {
            float4 w = *(float4*)&ws[kk][cg * 4];
            float xv[4];
            for (int i = 0; i < 4; i++) xv[i] = xs[rg * 4 + i][kt * 32 + kk];
            for (int i = 0; i < 4; i++) {
                acc[i][0] += xv[i] * w.x; acc[i][1] += xv[i] * w.y;
                acc[i][2] += xv[i] * w.z; acc[i][3] += xv[i] * w.w;
            }
        }
    }
    for (int i = 0; i < 4; i++) {
        int r = row0 + rg * 4 + i;
        if (r < N_NODES)
            *(float4*)&h[(size_t)r * 128 + cg * 4] =
                make_float4(acc[i][0], acc[i][1], acc[i][2], acc[i][3]);
    }
}

// ---------------- Aggregation, 128 channels (layer 1) ----------------
// Wave = 1 node. Half-waves handle even/odd edges; float4 (4 ch) per lane;
// 16 edges in flight. ushort local src idx; dinv[s] broadcast; dinv[d] hoisted.

__global__ __launch_bounds__(256) void k_agg128(const float* __restrict__ h,
                                                const int* __restrict__ rowptr,
                                                const unsigned short* __restrict__ ssrc,
                                                const float* __restrict__ dinv,
                                                const float* __restrict__ ba,
                                                const float* __restrict__ bx,
                                                float* __restrict__ outB) {
    int xcd = blockIdx.x & 7, slot = blockIdx.x >> 3;
    int gi = slot / 250, chunk = slot - gi * 250;
    int g = xcd + 8 * gi;
    if (g >= NB) return;
    int nl   = chunk * 4 + (threadIdx.x >> 6);   // local node 0..999
    int wid  = g * NPG + nl;
    int lane = threadIdx.x & 63;
    int sub = lane >> 5;           // 0: even edges, 1: odd edges
    int cl  = lane & 31;           // float4 channel group
    const float4* h4g = (const float4*)h + (size_t)g * NPG * 32;
    const float*  dvg = dinv + g * NPG;
    float4 acc = make_float4(0.f, 0.f, 0.f, 0.f);
    int e0 = rowptr[wid], e1 = rowptr[wid + 1];
    int e = e0;
    for (; e + 16 <= e1; e += 16) {
        int s[8];
        #pragma unroll
        for (int j = 0; j < 8; j++) s[j] = ssrc[e + 2 * j + sub];
        float dv[8];
        #pragma unroll
        for (int j = 0; j < 8; j++) dv[j] = dvg[s[j]];   // broadcast across half-wave
        float4 r[8];
        #pragma unroll
        for (int j = 0; j < 8; j++) r[j] = h4g[(size_t)s[j] * 32 + cl];
        #pragma unroll
        for (int j = 0; j < 8; j++) {
            acc.x += dv[j] * r[j].x; acc.y += dv[j] * r[j].y;
            acc.z += dv[j] * r[j].z; acc.w += dv[j] * r[j].w;
        }
    }
    for (; e < e1; e += 2) {
        int ee = e + sub;
        int ss = ssrc[e]; float dv = 0.0f;
        if (ee < e1) { ss = ssrc[ee]; dv = dvg[ss]; }
        float4 r = h4g[(size_t)ss * 32 + cl];
        acc.x += dv * r.x; acc.y += dv * r.y;
        acc.z += dv * r.z; acc.w += dv * r.w;
    }
    acc.x += __shfl_xor(acc.x, 32);
    acc.y += __shfl_xor(acc.y, 32);
    acc.z += __shfl_xor(acc.z, 32);
    acc.w += __shfl_xor(acc.w, 32);
    if (sub == 0) {
        float di = dvg[nl];
        float sw = 2.0f * di * di;
        float4 hv = h4g[(size_t)nl * 32 + cl];
        int cb = cl * 4;                       // group fully in ba or bx (64%4==0)
        const float* bb = (cb < 64) ? &ba[cb] : &bx[cb - 64];
        acc.x = fmaxf(di * acc.x + sw * hv.x + bb[0], 0.0f);
        acc.y = fmaxf(di * acc.y + sw * hv.y + bb[1], 0.0f);
        acc.z = fmaxf(di * acc.z + sw * hv.z + bb[2], 0.0f);
        acc.w = fmaxf(di * acc.w + sw * hv.w + bb[3], 0.0f);
        ((float4*)outB)[(size_t)wid * 32 + cl] = acc;
    }
}

// ---------------- Aggregation, 64 channels (layer 2) ----------------
// Quarter-waves handle edge j%4; float4 per lane; 32 edges in flight.
// cg<32: a-branch (+b_a2, no relu); cg>=32: x-branch (+b_x2, relu).

__global__ __launch_bounds__(256) void k_agg64(const float* __restrict__ g2,
                                               const int* __restrict__ rowptr,
                                               const unsigned short* __restrict__ ssrc,
                                               const float* __restrict__ dinv,
                                               const float* __restrict__ ba2,
                                               const float* __restrict__ bx2,
                                               float* __restrict__ s2) {
    int xcd = blockIdx.x & 7, slot = blockIdx.x >> 3;
    int gi = slot / 250, chunk = slot - gi * 250;
    int g = xcd + 8 * gi;
    if (g >= NB) return;
    int nl   = chunk * 4 + (threadIdx.x >> 6);
    int wid  = g * NPG + nl;
    int lane = threadIdx.x & 63;
    int sub = lane >> 4;           // 0..3: edge j%4
    int cl  = lane & 15;           // float4 channel group
    const float4* g4g = (const float4*)g2 + (size_t)g * NPG * 16;
    const float*  dvg = dinv + g * NPG;
    float4 acc = make_float4(0.f, 0.f, 0.f, 0.f);
    int e0 = rowptr[wid], e1 = rowptr[wid + 1];
    int e = e0;
    for (; e + 32 <= e1; e += 32) {
        int s[8];
        #pragma unroll
        for (int j = 0; j < 8; j++) s[j] = ssrc[e + 4 * j + sub];
        float dv[8];
        #pragma unroll
        for (int j = 0; j < 8; j++) dv[j] = dvg[s[j]];
        float4 r[8];
        #pragma unroll
        for (int j = 0; j < 8; j++) r[j] = g4g[(size_t)s[j] * 16 + cl];
        #pragma unroll
        for (int j = 0; j < 8; j++) {
            acc.x += dv[j] * r[j].x; acc.y += dv[j] * r[j].y;
            acc.z += dv[j] * r[j].z; acc.w += dv[j] * r[j].w;
        }
    }
    for (; e < e1; e += 4) {
        int ee = e + sub;
        int ss = ssrc[e]; float dv = 0.0f;
        if (ee < e1) { ss = ssrc[ee]; dv = dvg[ss]; }
        float4 r = g4g[(size_t)ss * 16 + cl];
        acc.x += dv * r.x; acc.y += dv * r.y;
        acc.z += dv * r.z; acc.w += dv * r.w;
    }
    acc.x += __shfl_xor(acc.x, 16); acc.x += __shfl_xor(acc.x, 32);
    acc.y += __shfl_xor(acc.y, 16); acc.y += __shfl_xor(acc.y, 32);
    acc.z += __shfl_xor(acc.z, 16); acc.z += __shfl_xor(acc.z, 32);
    acc.w += __shfl_xor(acc.w, 16); acc.w += __shfl_xor(acc.w, 32);
    if (sub == 0) {
        float di = dvg[nl];
        float sw = 2.0f * di * di;
        float4 hv = g4g[(size_t)nl * 16 + cl];
        int cb = cl * 4;                       // group fully in a or x (32%4==0)
        if (cb < 32) {
            acc.x = di * acc.x + sw * hv.x + ba2[cb + 0];
            acc.y = di * acc.y + sw * hv.y + ba2[cb + 1];
            acc.z = di * acc.z + sw * hv.z + ba2[cb + 2];
            acc.w = di * acc.w + sw * hv.w + ba2[cb + 3];
        } else {
            acc.x = fmaxf(di * acc.x + sw * hv.x + bx2[cb - 32 + 0], 0.0f);
            acc.y = fmaxf(di * acc.y + sw * hv.y + bx2[cb - 32 + 1], 0.0f);
            acc.z = fmaxf(di * acc.z + sw * hv.z + bx2[cb - 32 + 2], 0.0f);
            acc.w = fmaxf(di * acc.w + sw * hv.w + bx2[cb - 32 + 3], 0.0f);
        }
        ((float4*)s2)[(size_t)wid * 16 + cl] = acc;
    }
}

// ---------------- GEMM 2: g2 = [a1|x1] @ blockdiag(W_a2, W_x2) (64ch out) ----------------

__global__ __launch_bounds__(256) void k_gemm2(const float* __restrict__ Bm,
                                               const float* __restrict__ Wa2,
                                               const float* __restrict__ Wx2,
                                               float* __restrict__ g2) {
    __shared__ float xs[64][132];
    __shared__ float ws[64][68];
    int xcd = blockIdx.x & 7, slot = blockIdx.x >> 3;
    int g = xcd + 8 * (slot >> 4);
    int chunk = slot & 15;
    if (g >= NB) return;
    int row0 = g * NPG + chunk * 64;   // chunk 15 spills into next graph: benign dup
    int t = threadIdx.x;
    for (int i = 0; i < 4; i++) {
        int idx = t + 256 * i;
        int k = idx >> 4, c4 = idx & 15, c = c4 * 4;
        float4 v;
        if (c < 32) v = *(const float4*)&Wa2[k * 32 + c];
        else        v = *(const float4*)&Wx2[k * 32 + (c - 32)];
        *(float4*)&ws[k][c] = v;
    }
    for (int i = 0; i < 8; i++) {
        int idx = t + 256 * i;
        int r = idx >> 5, k4 = idx & 31;
        int rr = row0 + r; if (rr >= N_NODES) rr = N_NODES - 1;
        *(float4*)&xs[r][k4 * 4] = *(const float4*)&Bm[(size_t)rr * 128 + k4 * 4];
    }
    __syncthreads();
    int cg = t & 15, rg = t >> 4;
    int koff = (cg < 8) ? 0 : 64;
    float acc[4][4] = {};
    for (int k = 0; k < 64; k++) {
        float4 w = *(float4*)&ws[k][cg * 4];
        float xv[4];
        for (int i = 0; i < 4; i++) xv[i] = xs[rg * 4 + i][koff + k];
        for (int i = 0; i < 4; i++) {
            acc[i][0] += xv[i] * w.x; acc[i][1] += xv[i] * w.y;
            acc[i][2] += xv[i] * w.z; acc[i][3] += xv[i] * w.w;
        }
    }
    for (int i = 0; i < 4; i++) {
        int r = row0 + rg * 4 + i;
        if (r < N_NODES)
            *(float4*)&g2[(size_t)r * 64 + cg * 4] =
                make_float4(acc[i][0], acc[i][1], acc[i][2], acc[i][3]);
    }
}

// ---------------- Segment softmax stats (cols 0..31), per graph ----------------

__global__ __launch_bounds__(256) void k_smax(const float* __restrict__ s2,
                                              float* __restrict__ gmax,
                                              float* __restrict__ sinv) {
    __shared__ float red[8][32];
    int g = (blockIdx.x & 7) + 8 * (blockIdx.x >> 3);
    if (g >= NB) return;
    int t = threadIdx.x;
    int c = t & 31, sub = t >> 5;
    size_t base = (size_t)g * NPG;
    float m = -1e30f;
    for (int n = sub; n < NPG; n += 8)
        m = fmaxf(m, s2[(base + n) * 64 + c]);
    red[sub][c] = m; __syncthreads();
    if (sub == 0) {
        for (int j = 1; j < 8; j++) m = fmaxf(m, red[j][c]);
        red[0][c] = m;
        gmax[g * 32 + c] = m;
    }
    __syncthreads();
    m = red[0][c];
    __syncthreads();
    float sum = 0.0f;
    for (int n = sub; n < NPG; n += 8)
        sum += expf(s2[(base + n) * 64 + c] - m);
    red[sub][c] = sum; __syncthreads();
    if (sub == 0) {
        for (int j = 1; j < 8; j++) sum += red[j][c];
        sinv[g * 32 + c] = 1.0f / sum;
    }
}

// ---------------- Bilinear pool (spill-free; exp at staging) ----------------
// Direct per-chunk partial stores: prods[(g*4+ch)][1024]; no atomics/memset.

__global__ __launch_bounds__(256) void k_pool(const float* __restrict__ s2,
                                              const float* __restrict__ gmax,
                                              float* __restrict__ prods) {
    __shared__ float ta[50][32];
    __shared__ float tx[50][32];
    __shared__ float gm[32];
    int xcd = blockIdx.x & 7, slot = blockIdx.x >> 3;
    int g = xcd + 8 * (slot >> 2);
    int ch = slot & 3;
    if (g >= NB) return;
    int t = threadIdx.x;
    if (t < 32) gm[t] = gmax[g * 32 + t];
    int e  = t >> 3;
    int f4 = t & 7;
    float a0 = 0.f, a1 = 0.f, a2 = 0.f, a3 = 0.f;
    int base = g * NPG + ch * 250;
    for (int n0 = 0; n0 < 250; n0 += 50) {
        __syncthreads();
        for (int i = t; i < 50 * 16; i += 256) {
            int r = i >> 4, c4 = i & 15;
            float4 v = *(const float4*)&s2[(size_t)(base + n0 + r) * 64 + c4 * 4];
            if (c4 < 8) {
                int cb = c4 * 4;
                v.x = __expf(v.x - gm[cb + 0]);
                v.y = __expf(v.y - gm[cb + 1]);
                v.z = __expf(v.z - gm[cb + 2]);
                v.w = __expf(v.w - gm[cb + 3]);
                *(float4*)&ta[r][cb] = v;
            } else {
                *(float4*)&tx[r][(c4 - 8) * 4] = v;
            }
        }
        __syncthreads();
        #pragma unroll 5
        for (int n = 0; n < 50; n++) {
            float a   = ta[n][e];
            float4 xv = *(float4*)&tx[n][f4 * 4];
            a0 += a * xv.x; a1 += a * xv.y; a2 += a * xv.z; a3 += a * xv.w;
        }
    }
    *(float4*)&prods[((size_t)(g * 4 + ch)) * 1024 + e * 32 + f4 * 4] =
        make_float4(a0, a1, a2, a3);
}

// ---------------- Head: sum 4 chunk-partials, linear, softmax ----------------

__global__ __launch_bounds__(256) void k_head(const float* __restrict__ prods,
                                              const float* __restrict__ sinv,
                                              const float* __restrict__ Wlin,
                                              const float* __restrict__ blin,
                                              float* __restrict__ out) {
    __shared__ float red[4][NCLS];
    int g = (blockIdx.x & 7) + 8 * (blockIdx.x >> 3);
    if (g >= NB) return;
    int t = threadIdx.x;
    float p[NCLS];
    for (int c = 0; c < NCLS; c++) p[c] = 0.0f;
    const float* pg = &prods[(size_t)g * 4 * 1024];
    for (int j = 0; j < 4; j++) {
        int k = t * 4 + j;
        int e = k >> 5;
        float v = (pg[k] + pg[1024 + k] + pg[2048 + k] + pg[3072 + k]) * sinv[g * 32 + e];
        const float* wrow = &Wlin[(size_t)k * NCLS];
        for (int c = 0; c < NCLS; c++) p[c] += v * wrow[c];
    }
    for (int off = 32; off > 0; off >>= 1)
        for (int c = 0; c < NCLS; c++) p[c] += __shfl_down(p[c], off, 64);
    int wave = t >> 6, lane = t & 63;
    if (lane == 0)
        for (int c = 0; c < NCLS; c++) red[wave][c] = p[c];
    __syncthreads();
    if (t == 0) {
        float logits[NCLS]; float mx = -1e30f;
        for (int c = 0; c < NCLS; c++) {
            logits[c] = red[0][c] + red[1][c] + red[2][c] + red[3][c] + blin[c];
            mx = fmaxf(mx, logits[c]);
        }
        float s = 0.0f;
        for (int c = 0; c < NCLS; c++) { logits[c] = expf(logits[c] - mx); s += logits[c]; }
        float inv = 1.0f / s;
        for (int c = 0; c < NCLS; c++) out[g * NCLS + c] = logits[c] * inv;
    }
}

// ---------------- launch ----------------

extern "C" void kernel_launch(void* const* d_in, const int* in_sizes, int n_in,
                              void* d_out, int out_size, void* d_ws, size_t ws_size,
                              hipStream_t stream) {
    const float* x    = (const float*)d_in[0];
    const int*   ei   = (const int*)d_in[1];
    const float* Wa1  = (const float*)d_in[3];
    const float* ba1  = (const float*)d_in[4];
    const float* Wa2  = (const float*)d_in[5];
    const float* ba2  = (const float*)d_in[6];
    const float* Wx1  = (const float*)d_in[7];
    const float* bx1  = (const float*)d_in[8];
    const float* Wx2  = (const float*)d_in[9];
    const float* bx2  = (const float*)d_in[10];
    const float* Wlin = (const float*)d_in[11];
    const float* blin = (const float*)d_in[12];
    float* out = (float*)d_out;

    char* w = (char*)d_ws;
    auto alloc = [&](size_t bytes) -> void* {
        void* p = (void*)w;
        w += (bytes + 255) & ~(size_t)255;
        return p;
    };
    int*            rowptr = (int*)alloc((N_NODES + 1) * sizeof(int));
    float*          dinv   = (float*)alloc(N_NODES * sizeof(float));
    unsigned short* ssrc   = (unsigned short*)alloc((size_t)N_EDGES * sizeof(unsigned short));
    float*          gmax   = (float*)alloc(NB * DE * sizeof(float));
    float*          sinv   = (float*)alloc(NB * DE * sizeof(float));
    float*          prods  = (float*)alloc((size_t)NB * 4 * 1024 * sizeof(float));
    float*          bufA   = (float*)alloc((size_t)N_NODES * 128 * sizeof(float));
    float*          bufB   = (float*)alloc((size_t)N_NODES * 128 * sizeof(float));

    const int* srcp = ei;
    const int* dstp = ei + N_EDGES;

    k_sort<<<8 * 13, 256, 0, stream>>>(srcp, dstp, rowptr, dinv, ssrc);
    k_gemm1<<<8 * 13 * 32, 256, 0, stream>>>(x, Wa1, Wx1, bufA);
    k_agg128<<<8 * 13 * 250, 256, 0, stream>>>(bufA, rowptr, ssrc, dinv, ba1, bx1, bufB);
    k_gemm2<<<8 * 13 * 16, 256, 0, stream>>>(bufB, Wa2, Wx2, bufA);
    k_agg64<<<8 * 13 * 250, 256, 0, stream>>>(bufA, rowptr, ssrc, dinv, ba2, bx2, bufB);
    k_smax<<<8 * 13, 256, 0, stream>>>(bufB, gmax, sinv);
    k_pool<<<8 * 13 * 4, 256, 0, stream>>>(bufB, gmax, prods);
    k_head<<<8 * 13, 256, 0, stream>>>(prods, sinv, Wlin, blin, out);
}

// Round 10
// 439.378 us; speedup vs baseline: 1.6319x; 1.1523x over previous
//
#include <hip/hip_runtime.h>
#include <hip/hip_bf16.h>

#define N_NODES 100000
#define N_EDGES 3200000
#define NB      100
#define NPG     1000
#define EPG     32000    // edges per graph
#define DIN     128
#define DH      64
#define DE      32
#define NCLS    10

// XCD-affine swizzle: graph g lives on XCD g%8 (blockIdx%8 = dispatch
// round-robin), keeping each graph's working set in ONE XCD's 4MB L2.
// R3 evidence: agg FETCH 254->38 MB.
// Aggregation = node-per-wave PULL gather from L2 with float4 sub-wave reads
// (R7 structure; R5 LDS-pull and R6 LDS-push both regressed >4x).
// R9: per-graph LDS counting sort replaced the 7-kernel CSR chain (717->506).
// R10: k_sort was wave-starved (4 waves/block, VALUBusy 1%) -> 1024 threads.

// ---------------- Per-graph CSR build, entirely in LDS ----------------
// One 1024-thread block per graph. Produces rowptr (global edge offsets),
// dinv, and the dst-sorted ushort src-index list. Zero global atomics.

__global__ __launch_bounds__(1024) void k_sort(const int* __restrict__ src,
                                               const int* __restrict__ dst,
                                               int* __restrict__ rowptr,
                                               float* __restrict__ dinv,
                                               unsigned short* __restrict__ ssrc) {
    __shared__ __align__(16) unsigned short buf[EPG];  // 64 KB sorted output
    __shared__ int cnt[NPG];                            // histogram
    __shared__ int pre[NPG];                            // exclusive prefix -> fill
    __shared__ int sm[1024];
    int g = (blockIdx.x & 7) + 8 * (blockIdx.x >> 3);
    if (g >= NB) return;
    int t = threadIdx.x;
    int ebase = g * EPG, nbase = g * NPG;
    if (t < NPG) cnt[t] = 0;
    __syncthreads();
    for (int i = t; i < EPG; i += 1024)
        atomicAdd(&cnt[dst[ebase + i] - nbase], 1);
    __syncthreads();
    int v = (t < NPG) ? cnt[t] : 0;
    if (t < NPG) dinv[nbase + t] = rsqrtf((float)v + 2.0f);
    // 1024-wide Hillis-Steele inclusive scan; thread t owns cnt[t]
    sm[t] = v;
    __syncthreads();
    for (int off = 1; off < 1024; off <<= 1) {
        int x = (t >= off) ? sm[t - off] : 0;
        __syncthreads();
        sm[t] += x;
        __syncthreads();
    }
    if (t < NPG) {
        int ex = sm[t] - v;               // exclusive prefix
        pre[t] = ex;
        rowptr[nbase + t] = ebase + ex;
    }
    if (g == NB - 1 && t == 0) rowptr[N_NODES] = N_EDGES;
    __syncthreads();
    // scatter into LDS (pre[] doubles as fill counters)
    for (int i = t; i < EPG; i += 1024) {
        int e = ebase + i;
        int d = dst[e] - nbase;
        int s = src[e] - nbase;
        int pos = atomicAdd(&pre[d], 1);
        buf[pos] = (unsigned short)s;
    }
    __syncthreads();
    // coalesced 16B/lane writeout
    uint4* gout = (uint4*)(ssrc + ebase);
    const uint4* lbuf = (const uint4*)buf;
    for (int i = t; i < EPG / 8; i += 1024)   // 4000 x 16B
        gout[i] = lbuf[i];
}

// ---------------- GEMM 1: h = x @ [W_a1 | W_x1]  (128 -> 128) ----------------

__global__ __launch_bounds__(256) void k_gemm1(const float* __restrict__ x,
                                               const float* __restrict__ Wa,
                                               const float* __restrict__ Wx,
                                               float* __restrict__ h) {
    __shared__ float xs[32][128];
    __shared__ float ws[32][128];
    int xcd = blockIdx.x & 7, slot = blockIdx.x >> 3;
    int g = xcd + 8 * (slot >> 5);
    int chunk = slot & 31;
    if (g >= NB) return;
    int row0 = g * NPG + chunk * 32;
    int t = threadIdx.x;
    for (int i = 0; i < 4; i++) {
        int idx = t + 256 * i;
        int r = idx >> 5, k4 = idx & 31;
        int rr = row0 + r; if (rr >= N_NODES) rr = N_NODES - 1;
        *(float4*)&xs[r][k4 * 4] = *(const float4*)&x[(size_t)rr * 128 + k4 * 4];
    }
    float acc[4][4] = {};
    int rg = t >> 5, cg = t & 31;
    for (int kt = 0; kt < 4; kt++) {
        __syncthreads();
        for (int i = 0; i < 4; i++) {
            int idx = t + 256 * i;
            int kk = idx >> 5, c4 = idx & 31;
            int k = kt * 32 + kk, c = c4 * 4;
            float4 v;
            if (c < 64) v = *(const float4*)&Wa[k * 64 + c];
            else        v = *(const float4*)&Wx[k * 64 + (c - 64)];
            *(float4*)&ws[kk][c] = v;
        }
        __syncthreads();
        for (int kk = 0; kk < 32; kk++) {
            float4 w = *(float4*)&ws[kk][cg * 4];
            float xv[4];
            for (int i = 0; i < 4; i++) xv[i] = xs[rg * 4 + i][kt * 32 + kk];
            for (int i = 0; i < 4; i++) {
                acc[i][0] += xv[i] * w.x; acc[i][1] += xv[i] * w.y;
                acc[i][2] += xv[i] * w.z; acc[i][3] += xv[i] * w.w;
            }
        }
    }
    for (int i = 0; i < 4; i++) {
        int r = row0 + rg * 4 + i;
        if (r < N_NODES)
            *(float4*)&h[(size_t)r * 128 + cg * 4] =
                make_float4(acc[i][0], acc[i][1], acc[i][2], acc[i][3]);
    }
}

// ---------------- Aggregation, 128 channels (layer 1) ----------------
// Wave = 1 node. Half-waves handle even/odd edges; float4 (4 ch) per lane;
// 16 edges in flight. ushort local src idx; dinv[s] broadcast; dinv[d] hoisted.

__global__ __launch_bounds__(256) void k_agg128(const float* __restrict__ h,
                                                const int* __restrict__ rowptr,
                                                const unsigned short* __restrict__ ssrc,
                                                const float* __restrict__ dinv,
                                                const float* __restrict__ ba,
                                                const float* __restrict__ bx,
                                                float* __restrict__ outB) {
    int xcd = blockIdx.x & 7, slot = blockIdx.x >> 3;
    int gi = slot / 250, chunk = slot - gi * 250;
    int g = xcd + 8 * gi;
    if (g >= NB) return;
    int nl   = chunk * 4 + (threadIdx.x >> 6);   // local node 0..999
    int wid  = g * NPG + nl;
    int lane = threadIdx.x & 63;
    int sub = lane >> 5;           // 0: even edges, 1: odd edges
    int cl  = lane & 31;           // float4 channel group
    const float4* h4g = (const float4*)h + (size_t)g * NPG * 32;
    const float*  dvg = dinv + g * NPG;
    float4 acc = make_float4(0.f, 0.f, 0.f, 0.f);
    int e0 = rowptr[wid], e1 = rowptr[wid + 1];
    int e = e0;
    for (; e + 16 <= e1; e += 16) {
        int s[8];
        #pragma unroll
        for (int j = 0; j < 8; j++) s[j] = ssrc[e + 2 * j + sub];
        float dv[8];
        #pragma unroll
        for (int j = 0; j < 8; j++) dv[j] = dvg[s[j]];   // broadcast across half-wave
        float4 r[8];
        #pragma unroll
        for (int j = 0; j < 8; j++) r[j] = h4g[(size_t)s[j] * 32 + cl];
        #pragma unroll
        for (int j = 0; j < 8; j++) {
            acc.x += dv[j] * r[j].x; acc.y += dv[j] * r[j].y;
            acc.z += dv[j] * r[j].z; acc.w += dv[j] * r[j].w;
        }
    }
    for (; e < e1; e += 2) {
        int ee = e + sub;
        int ss = ssrc[e]; float dv = 0.0f;
        if (ee < e1) { ss = ssrc[ee]; dv = dvg[ss]; }
        float4 r = h4g[(size_t)ss * 32 + cl];
        acc.x += dv * r.x; acc.y += dv * r.y;
        acc.z += dv * r.z; acc.w += dv * r.w;
    }
    acc.x += __shfl_xor(acc.x, 32);
    acc.y += __shfl_xor(acc.y, 32);
    acc.z += __shfl_xor(acc.z, 32);
    acc.w += __shfl_xor(acc.w, 32);
    if (sub == 0) {
        float di = dvg[nl];
        float sw = 2.0f * di * di;
        float4 hv = h4g[(size_t)nl * 32 + cl];
        int cb = cl * 4;                       // group fully in ba or bx (64%4==0)
        const float* bb = (cb < 64) ? &ba[cb] : &bx[cb - 64];
        acc.x = fmaxf(di * acc.x + sw * hv.x + bb[0], 0.0f);
        acc.y = fmaxf(di * acc.y + sw * hv.y + bb[1], 0.0f);
        acc.z = fmaxf(di * acc.z + sw * hv.z + bb[2], 0.0f);
        acc.w = fmaxf(di * acc.w + sw * hv.w + bb[3], 0.0f);
        ((float4*)outB)[(size_t)wid * 32 + cl] = acc;
    }
}

// ---------------- Aggregation, 64 channels (layer 2) ----------------
// Quarter-waves handle edge j%4; float4 per lane; 32 edges in flight.
// cg<32: a-branch (+b_a2, no relu); cg>=32: x-branch (+b_x2, relu).

__global__ __launch_bounds__(256) void k_agg64(const float* __restrict__ g2,
                                               const int* __restrict__ rowptr,
                                               const unsigned short* __restrict__ ssrc,
                                               const float* __restrict__ dinv,
                                               const float* __restrict__ ba2,
                                               const float* __restrict__ bx2,
                                               float* __restrict__ s2) {
    int xcd = blockIdx.x & 7, slot = blockIdx.x >> 3;
    int gi = slot / 250, chunk = slot - gi * 250;
    int g = xcd + 8 * gi;
    if (g >= NB) return;
    int nl   = chunk * 4 + (threadIdx.x >> 6);
    int wid  = g * NPG + nl;
    int lane = threadIdx.x & 63;
    int sub = lane >> 4;           // 0..3: edge j%4
    int cl  = lane & 15;           // float4 channel group
    const float4* g4g = (const float4*)g2 + (size_t)g * NPG * 16;
    const float*  dvg = dinv + g * NPG;
    float4 acc = make_float4(0.f, 0.f, 0.f, 0.f);
    int e0 = rowptr[wid], e1 = rowptr[wid + 1];
    int e = e0;
    for (; e + 32 <= e1; e += 32) {
        int s[8];
        #pragma unroll
        for (int j = 0; j < 8; j++) s[j] = ssrc[e + 4 * j + sub];
        float dv[8];
        #pragma unroll
        for (int j = 0; j < 8; j++) dv[j] = dvg[s[j]];
        float4 r[8];
        #pragma unroll
        for (int j = 0; j < 8; j++) r[j] = g4g[(size_t)s[j] * 16 + cl];
        #pragma unroll
        for (int j = 0; j < 8; j++) {
            acc.x += dv[j] * r[j].x; acc.y += dv[j] * r[j].y;
            acc.z += dv[j] * r[j].z; acc.w += dv[j] * r[j].w;
        }
    }
    for (; e < e1; e += 4) {
        int ee = e + sub;
        int ss = ssrc[e]; float dv = 0.0f;
        if (ee < e1) { ss = ssrc[ee]; dv = dvg[ss]; }
        float4 r = g4g[(size_t)ss * 16 + cl];
        acc.x += dv * r.x; acc.y += dv * r.y;
        acc.z += dv * r.z; acc.w += dv * r.w;
    }
    acc.x += __shfl_xor(acc.x, 16); acc.x += __shfl_xor(acc.x, 32);
    acc.y += __shfl_xor(acc.y, 16); acc.y += __shfl_xor(acc.y, 32);
    acc.z += __shfl_xor(acc.z, 16); acc.z += __shfl_xor(acc.z, 32);
    acc.w += __shfl_xor(acc.w, 16); acc.w += __shfl_xor(acc.w, 32);
    if (sub == 0) {
        float di = dvg[nl];
        float sw = 2.0f * di * di;
        float4 hv = g4g[(size_t)nl * 16 + cl];
        int cb = cl * 4;                       // group fully in a or x (32%4==0)
        if (cb < 32) {
            acc.x = di * acc.x + sw * hv.x + ba2[cb + 0];
            acc.y = di * acc.y + sw * hv.y + ba2[cb + 1];
            acc.z = di * acc.z + sw * hv.z + ba2[cb + 2];
            acc.w = di * acc.w + sw * hv.w + ba2[cb + 3];
        } else {
            acc.x = fmaxf(di * acc.x + sw * hv.x + bx2[cb - 32 + 0], 0.0f);
            acc.y = fmaxf(di * acc.y + sw * hv.y + bx2[cb - 32 + 1], 0.0f);
            acc.z = fmaxf(di * acc.z + sw * hv.z + bx2[cb - 32 + 2], 0.0f);
            acc.w = fmaxf(di * acc.w + sw * hv.w + bx2[cb - 32 + 3], 0.0f);
        }
        ((float4*)s2)[(size_t)wid * 16 + cl] = acc;
    }
}

// ---------------- GEMM 2: g2 = [a1|x1] @ blockdiag(W_a2, W_x2) (64ch out) ----------------

__global__ __launch_bounds__(256) void k_gemm2(const float* __restrict__ Bm,
                                               const float* __restrict__ Wa2,
                                               const float* __restrict__ Wx2,
                                               float* __restrict__ g2) {
    __shared__ float xs[64][132];
    __shared__ float ws[64][68];
    int xcd = blockIdx.x & 7, slot = blockIdx.x >> 3;
    int g = xcd + 8 * (slot >> 4);
    int chunk = slot & 15;
    if (g >= NB) return;
    int row0 = g * NPG + chunk * 64;   // chunk 15 spills into next graph: benign dup
    int t = threadIdx.x;
    for (int i = 0; i < 4; i++) {
        int idx = t + 256 * i;
        int k = idx >> 4, c4 = idx & 15, c = c4 * 4;
        float4 v;
        if (c < 32) v = *(const float4*)&Wa2[k * 32 + c];
        else        v = *(const float4*)&Wx2[k * 32 + (c - 32)];
        *(float4*)&ws[k][c] = v;
    }
    for (int i = 0; i < 8; i++) {
        int idx = t + 256 * i;
        int r = idx >> 5, k4 = idx & 31;
        int rr = row0 + r; if (rr >= N_NODES) rr = N_NODES - 1;
        *(float4*)&xs[r][k4 * 4] = *(const float4*)&Bm[(size_t)rr * 128 + k4 * 4];
    }
    __syncthreads();
    int cg = t & 15, rg = t >> 4;
    int koff = (cg < 8) ? 0 : 64;
    float acc[4][4] = {};
    for (int k = 0; k < 64; k++) {
        float4 w = *(float4*)&ws[k][cg * 4];
        float xv[4];
        for (int i = 0; i < 4; i++) xv[i] = xs[rg * 4 + i][koff + k];
        for (int i = 0; i < 4; i++) {
            acc[i][0] += xv[i] * w.x; acc[i][1] += xv[i] * w.y;
            acc[i][2] += xv[i] * w.z; acc[i][3] += xv[i] * w.w;
        }
    }
    for (int i = 0; i < 4; i++) {
        int r = row0 + rg * 4 + i;
        if (r < N_NODES)
            *(float4*)&g2[(size_t)r * 64 + cg * 4] =
                make_float4(acc[i][0], acc[i][1], acc[i][2], acc[i][3]);
    }
}

// ---------------- Segment softmax stats (cols 0..31), per graph ----------------

__global__ __launch_bounds__(256) void k_smax(const float* __restrict__ s2,
                                              float* __restrict__ gmax,
                                              float* __restrict__ sinv) {
    __shared__ float red[8][32];
    int g = (blockIdx.x & 7) + 8 * (blockIdx.x >> 3);
    if (g >= NB) return;
    int t = threadIdx.x;
    int c = t & 31, sub = t >> 5;
    size_t base = (size_t)g * NPG;
    float m = -1e30f;
    for (int n = sub; n < NPG; n += 8)
        m = fmaxf(m, s2[(base + n) * 64 + c]);
    red[sub][c] = m; __syncthreads();
    if (sub == 0) {
        for (int j = 1; j < 8; j++) m = fmaxf(m, red[j][c]);
        red[0][c] = m;
        gmax[g * 32 + c] = m;
    }
    __syncthreads();
    m = red[0][c];
    __syncthreads();
    float sum = 0.0f;
    for (int n = sub; n < NPG; n += 8)
        sum += expf(s2[(base + n) * 64 + c] - m);
    red[sub][c] = sum; __syncthreads();
    if (sub == 0) {
        for (int j = 1; j < 8; j++) sum += red[j][c];
        sinv[g * 32 + c] = 1.0f / sum;
    }
}

// ---------------- Bilinear pool (spill-free; exp at staging) ----------------
// Direct per-chunk partial stores: prods[(g*4+ch)][1024]; no atomics/memset.

__global__ __launch_bounds__(256) void k_pool(const float* __restrict__ s2,
                                              const float* __restrict__ gmax,
                                              float* __restrict__ prods) {
    __shared__ float ta[50][32];
    __shared__ float tx[50][32];
    __shared__ float gm[32];
    int xcd = blockIdx.x & 7, slot = blockIdx.x >> 3;
    int g = xcd + 8 * (slot >> 2);
    int ch = slot & 3;
    if (g >= NB) return;
    int t = threadIdx.x;
    if (t < 32) gm[t] = gmax[g * 32 + t];
    int e  = t >> 3;
    int f4 = t & 7;
    float a0 = 0.f, a1 = 0.f, a2 = 0.f, a3 = 0.f;
    int base = g * NPG + ch * 250;
    for (int n0 = 0; n0 < 250; n0 += 50) {
        __syncthreads();
        for (int i = t; i < 50 * 16; i += 256) {
            int r = i >> 4, c4 = i & 15;
            float4 v = *(const float4*)&s2[(size_t)(base + n0 + r) * 64 + c4 * 4];
            if (c4 < 8) {
                int cb = c4 * 4;
                v.x = __expf(v.x - gm[cb + 0]);
                v.y = __expf(v.y - gm[cb + 1]);
                v.z = __expf(v.z - gm[cb + 2]);
                v.w = __expf(v.w - gm[cb + 3]);
                *(float4*)&ta[r][cb] = v;
            } else {
                *(float4*)&tx[r][(c4 - 8) * 4] = v;
            }
        }
        __syncthreads();
        #pragma unroll 5
        for (int n = 0; n < 50; n++) {
            float a   = ta[n][e];
            float4 xv = *(float4*)&tx[n][f4 * 4];
            a0 += a * xv.x; a1 += a * xv.y; a2 += a * xv.z; a3 += a * xv.w;
        }
    }
    *(float4*)&prods[((size_t)(g * 4 + ch)) * 1024 + e * 32 + f4 * 4] =
        make_float4(a0, a1, a2, a3);
}

// ---------------- Head: sum 4 chunk-partials, linear, softmax ----------------

__global__ __launch_bounds__(256) void k_head(const float* __restrict__ prods,
                                              const float* __restrict__ sinv,
                                              const float* __restrict__ Wlin,
                                              const float* __restrict__ blin,
                                              float* __restrict__ out) {
    __shared__ float red[4][NCLS];
    int g = (blockIdx.x & 7) + 8 * (blockIdx.x >> 3);
    if (g >= NB) return;
    int t = threadIdx.x;
    float p[NCLS];
    for (int c = 0; c < NCLS; c++) p[c] = 0.0f;
    const float* pg = &prods[(size_t)g * 4 * 1024];
    for (int j = 0; j < 4; j++) {
        int k = t * 4 + j;
        int e = k >> 5;
        float v = (pg[k] + pg[1024 + k] + pg[2048 + k] + pg[3072 + k]) * sinv[g * 32 + e];
        const float* wrow = &Wlin[(size_t)k * NCLS];
        for (int c = 0; c < NCLS; c++) p[c] += v * wrow[c];
    }
    for (int off = 32; off > 0; off >>= 1)
        for (int c = 0; c < NCLS; c++) p[c] += __shfl_down(p[c], off, 64);
    int wave = t >> 6, lane = t & 63;
    if (lane == 0)
        for (int c = 0; c < NCLS; c++) red[wave][c] = p[c];
    __syncthreads();
    if (t == 0) {
        float logits[NCLS]; float mx = -1e30f;
        for (int c = 0; c < NCLS; c++) {
            logits[c] = red[0][c] + red[1][c] + red[2][c] + red[3][c] + blin[c];
            mx = fmaxf(mx, logits[c]);
        }
        float s = 0.0f;
        for (int c = 0; c < NCLS; c++) { logits[c] = expf(logits[c] - mx); s += logits[c]; }
        float inv = 1.0f / s;
        for (int c = 0; c < NCLS; c++) out[g * NCLS + c] = logits[c] * inv;
    }
}

// ---------------- launch ----------------

extern "C" void kernel_launch(void* const* d_in, const int* in_sizes, int n_in,
                              void* d_out, int out_size, void* d_ws, size_t ws_size,
                              hipStream_t stream) {
    const float* x    = (const float*)d_in[0];
    const int*   ei   = (const int*)d_in[1];
    const float* Wa1  = (const float*)d_in[3];
    const float* ba1  = (const float*)d_in[4];
    const float* Wa2  = (const float*)d_in[5];
    const float* ba2  = (const float*)d_in[6];
    const float* Wx1  = (const float*)d_in[7];
    const float* bx1  = (const float*)d_in[8];
    const float* Wx2  = (const float*)d_in[9];
    const float* bx2  = (const float*)d_in[10];
    const float* Wlin = (const float*)d_in[11];
    const float* blin = (const float*)d_in[12];
    float* out = (float*)d_out;

    char* w = (char*)d_ws;
    auto alloc = [&](size_t bytes) -> void* {
        void* p = (void*)w;
        w += (bytes + 255) & ~(size_t)255;
        return p;
    };
    int*            rowptr = (int*)alloc((N_NODES + 1) * sizeof(int));
    float*          dinv   = (float*)alloc(N_NODES * sizeof(float));
    unsigned short* ssrc   = (unsigned short*)alloc((size_t)N_EDGES * sizeof(unsigned short));
    float*          gmax   = (float*)alloc(NB * DE * sizeof(float));
    float*          sinv   = (float*)alloc(NB * DE * sizeof(float));
    float*          prods  = (float*)alloc((size_t)NB * 4 * 1024 * sizeof(float));
    float*          bufA   = (float*)alloc((size_t)N_NODES * 128 * sizeof(float));
    float*          bufB   = (float*)alloc((size_t)N_NODES * 128 * sizeof(float));

    const int* srcp = ei;
    const int* dstp = ei + N_EDGES;

    k_sort<<<8 * 13, 1024, 0, stream>>>(srcp, dstp, rowptr, dinv, ssrc);
    k_gemm1<<<8 * 13 * 32, 256, 0, stream>>>(x, Wa1, Wx1, bufA);
    k_agg128<<<8 * 13 * 250, 256, 0, stream>>>(bufA, rowptr, ssrc, dinv, ba1, bx1, bufB);
    k_gemm2<<<8 * 13 * 16, 256, 0, stream>>>(bufB, Wa2, Wx2, bufA);
    k_agg64<<<8 * 13 * 250, 256, 0, stream>>>(bufA, rowptr, ssrc, dinv, ba2, bx2, bufB);
    k_smax<<<8 * 13, 256, 0, stream>>>(bufB, gmax, sinv);
    k_pool<<<8 * 13 * 4, 256, 0, stream>>>(bufB, gmax, prods);
    k_head<<<8 * 13, 256, 0, stream>>>(prods, sinv, Wlin, blin, out);
}

// Round 11
// 399.661 us; speedup vs baseline: 1.7941x; 1.0994x over previous
//
#include <hip/hip_runtime.h>
#include <hip/hip_bf16.h>
#include <hip/hip_fp16.h>

#define N_NODES 100000
#define N_EDGES 3200000
#define NB      100
#define NPG     1000
#define EPG     32000    // edges per graph
#define DIN     128
#define DH      64
#define DE      32
#define NCLS    10

// XCD-affine swizzle: graph g lives on XCD g%8 (blockIdx%8 = dispatch
// round-robin), keeping each graph's working set in ONE XCD's 4MB L2.
// Aggregation = node-per-wave PULL gather from L2 (R7; LDS pull/push both
// regressed >4x). R9/R10: one-kernel LDS counting sort for CSR (1024 thr).
// R11: gather rows stored fp16 (gemm outputs packed __half) -- halves the
// L2 gather stream (R10 evidence: agg128 at 26 B/cyc/CU ~= random-access L2
// ceiling; bytes/edge is the wall). Accumulation stays fp32; fp16 rounding
// (~5e-4 rel) keeps final softmax error ~2e-4 << 2.19e-3 threshold.

// ---------------- Per-graph CSR build, entirely in LDS ----------------

__global__ __launch_bounds__(1024) void k_sort(const int* __restrict__ src,
                                               const int* __restrict__ dst,
                                               int* __restrict__ rowptr,
                                               float* __restrict__ dinv,
                                               unsigned short* __restrict__ ssrc) {
    __shared__ __align__(16) unsigned short buf[EPG];  // 64 KB sorted output
    __shared__ int cnt[NPG];
    __shared__ int pre[NPG];
    __shared__ int sm[1024];
    int g = (blockIdx.x & 7) + 8 * (blockIdx.x >> 3);
    if (g >= NB) return;
    int t = threadIdx.x;
    int ebase = g * EPG, nbase = g * NPG;
    if (t < NPG) cnt[t] = 0;
    __syncthreads();
    for (int i = t; i < EPG; i += 1024)
        atomicAdd(&cnt[dst[ebase + i] - nbase], 1);
    __syncthreads();
    int v = (t < NPG) ? cnt[t] : 0;
    if (t < NPG) dinv[nbase + t] = rsqrtf((float)v + 2.0f);
    sm[t] = v;
    __syncthreads();
    for (int off = 1; off < 1024; off <<= 1) {
        int x = (t >= off) ? sm[t - off] : 0;
        __syncthreads();
        sm[t] += x;
        __syncthreads();
    }
    if (t < NPG) {
        int ex = sm[t] - v;
        pre[t] = ex;
        rowptr[nbase + t] = ebase + ex;
    }
    if (g == NB - 1 && t == 0) rowptr[N_NODES] = N_EDGES;
    __syncthreads();
    for (int i = t; i < EPG; i += 1024) {
        int e = ebase + i;
        int d = dst[e] - nbase;
        int s = src[e] - nbase;
        int pos = atomicAdd(&pre[d], 1);
        buf[pos] = (unsigned short)s;
    }
    __syncthreads();
    uint4* gout = (uint4*)(ssrc + ebase);
    const uint4* lbuf = (const uint4*)buf;
    for (int i = t; i < EPG / 8; i += 1024)
        gout[i] = lbuf[i];
}

// ---------------- GEMM 1: h16 = fp16( x @ [W_a1 | W_x1] ) ----------------

__global__ __launch_bounds__(256) void k_gemm1(const float* __restrict__ x,
                                               const float* __restrict__ Wa,
                                               const float* __restrict__ Wx,
                                               unsigned short* __restrict__ h16) {
    __shared__ float xs[32][128];
    __shared__ float ws[32][128];
    int xcd = blockIdx.x & 7, slot = blockIdx.x >> 3;
    int g = xcd + 8 * (slot >> 5);
    int chunk = slot & 31;
    if (g >= NB) return;
    int row0 = g * NPG + chunk * 32;
    int t = threadIdx.x;
    for (int i = 0; i < 4; i++) {
        int idx = t + 256 * i;
        int r = idx >> 5, k4 = idx & 31;
        int rr = row0 + r; if (rr >= N_NODES) rr = N_NODES - 1;
        *(float4*)&xs[r][k4 * 4] = *(const float4*)&x[(size_t)rr * 128 + k4 * 4];
    }
    float acc[4][4] = {};
    int rg = t >> 5, cg = t & 31;
    for (int kt = 0; kt < 4; kt++) {
        __syncthreads();
        for (int i = 0; i < 4; i++) {
            int idx = t + 256 * i;
            int kk = idx >> 5, c4 = idx & 31;
            int k = kt * 32 + kk, c = c4 * 4;
            float4 v;
            if (c < 64) v = *(const float4*)&Wa[k * 64 + c];
            else        v = *(const float4*)&Wx[k * 64 + (c - 64)];
            *(float4*)&ws[kk][c] = v;
        }
        __syncthreads();
        for (int kk = 0; kk < 32; kk++) {
            float4 w = *(float4*)&ws[kk][cg * 4];
            float xv[4];
            for (int i = 0; i < 4; i++) xv[i] = xs[rg * 4 + i][kt * 32 + kk];
            for (int i = 0; i < 4; i++) {
                acc[i][0] += xv[i] * w.x; acc[i][1] += xv[i] * w.y;
                acc[i][2] += xv[i] * w.z; acc[i][3] += xv[i] * w.w;
            }
        }
    }
    for (int i = 0; i < 4; i++) {
        int r = row0 + rg * 4 + i;
        if (r < N_NODES) {
            union { ushort4 u; __half2 h[2]; } pk;
            pk.h[0] = __floats2half2_rn(acc[i][0], acc[i][1]);
            pk.h[1] = __floats2half2_rn(acc[i][2], acc[i][3]);
            *(ushort4*)&h16[(size_t)r * 128 + cg * 4] = pk.u;
        }
    }
}

// ---------------- Aggregation, 128 channels (layer 1), fp16 gather ----------------
// Wave = 1 node. Lane = (sub 0..3 edge-parallel, cl 0..15 8-ch group of 16B).
// 16 rows in flight per wave; fp32 accumulate; shfl_xor(16,32) combine.

__global__ __launch_bounds__(256) void k_agg128(const unsigned short* __restrict__ h16,
                                                const int* __restrict__ rowptr,
                                                const unsigned short* __restrict__ ssrc,
                                                const float* __restrict__ dinv,
                                                const float* __restrict__ ba,
                                                const float* __restrict__ bx,
                                                float* __restrict__ outB) {
    int xcd = blockIdx.x & 7, slot = blockIdx.x >> 3;
    int gi = slot / 250, chunk = slot - gi * 250;
    int g = xcd + 8 * gi;
    if (g >= NB) return;
    int nl   = chunk * 4 + (threadIdx.x >> 6);   // local node 0..999
    int wid  = g * NPG + nl;
    int lane = threadIdx.x & 63;
    int sub = lane >> 4;           // 0..3: edge j%4
    int cl  = lane & 15;           // 8-channel group (16 B)
    const unsigned short* hg = h16 + (size_t)g * NPG * 128;
    const float* dvg = dinv + g * NPG;
    float acc[8] = {};
    union U8 { uint4 u; __half2 h[4]; };
    int e0 = rowptr[wid], e1 = rowptr[wid + 1];
    int e = e0;
    for (; e + 16 <= e1; e += 16) {
        int s[4]; float dv[4]; U8 r[4];
        #pragma unroll
        for (int j = 0; j < 4; j++) s[j] = ssrc[e + 4 * j + sub];
        #pragma unroll
        for (int j = 0; j < 4; j++) dv[j] = dvg[s[j]];     // broadcast
        #pragma unroll
        for (int j = 0; j < 4; j++) r[j].u = *(const uint4*)&hg[(size_t)s[j] * 128 + cl * 8];
        #pragma unroll
        for (int j = 0; j < 4; j++) {
            #pragma unroll
            for (int k = 0; k < 4; k++) {
                float2 f = __half22float2(r[j].h[k]);
                acc[2 * k]     += dv[j] * f.x;
                acc[2 * k + 1] += dv[j] * f.y;
            }
        }
    }
    for (; e + 8 <= e1; e += 8) {
        #pragma unroll
        for (int j = 0; j < 2; j++) {
            int ss = ssrc[e + 4 * j + sub];
            float dv = dvg[ss];
            U8 r; r.u = *(const uint4*)&hg[(size_t)ss * 128 + cl * 8];
            #pragma unroll
            for (int k = 0; k < 4; k++) {
                float2 f = __half22float2(r.h[k]);
                acc[2 * k]     += dv * f.x;
                acc[2 * k + 1] += dv * f.y;
            }
        }
    }
    for (; e < e1; e += 4) {
        int ee = e + sub;
        int ss; float dv;
        if (ee < e1) { ss = ssrc[ee]; dv = dvg[ss]; }
        else         { ss = ssrc[e];  dv = 0.0f; }
        U8 r; r.u = *(const uint4*)&hg[(size_t)ss * 128 + cl * 8];
        #pragma unroll
        for (int k = 0; k < 4; k++) {
            float2 f = __half22float2(r.h[k]);
            acc[2 * k]     += dv * f.x;
            acc[2 * k + 1] += dv * f.y;
        }
    }
    #pragma unroll
    for (int k = 0; k < 8; k++) {
        acc[k] += __shfl_xor(acc[k], 16);
        acc[k] += __shfl_xor(acc[k], 32);
    }
    if (sub == 0) {
        float di = dvg[nl];
        float sw = 2.0f * di * di;
        U8 hv; hv.u = *(const uint4*)&hg[(size_t)nl * 128 + cl * 8];
        int cb = cl * 8;                     // 64%8==0: group fully in ba or bx
        const float* bb = (cb < 64) ? &ba[cb] : &bx[cb - 64];
        float o[8];
        #pragma unroll
        for (int k = 0; k < 4; k++) {
            float2 f = __half22float2(hv.h[k]);
            o[2 * k]     = fmaxf(di * acc[2 * k]     + sw * f.x + bb[2 * k],     0.0f);
            o[2 * k + 1] = fmaxf(di * acc[2 * k + 1] + sw * f.y + bb[2 * k + 1], 0.0f);
        }
        *(float4*)&outB[(size_t)wid * 128 + cb]     = make_float4(o[0], o[1], o[2], o[3]);
        *(float4*)&outB[(size_t)wid * 128 + cb + 4] = make_float4(o[4], o[5], o[6], o[7]);
    }
}

// ---------------- Aggregation, 64 channels (layer 2), fp16 gather ----------------
// Lane = (sub 0..7 edge-parallel, cl 0..7 8-ch group). shfl_xor(8,16,32).
// cg<32: a-branch (+b_a2, no relu); cg>=32: x-branch (+b_x2, relu).

__global__ __launch_bounds__(256) void k_agg64(const unsigned short* __restrict__ g16,
                                               const int* __restrict__ rowptr,
                                               const unsigned short* __restrict__ ssrc,
                                               const float* __restrict__ dinv,
                                               const float* __restrict__ ba2,
                                               const float* __restrict__ bx2,
                                               float* __restrict__ s2) {
    int xcd = blockIdx.x & 7, slot = blockIdx.x >> 3;
    int gi = slot / 250, chunk = slot - gi * 250;
    int g = xcd + 8 * gi;
    if (g >= NB) return;
    int nl   = chunk * 4 + (threadIdx.x >> 6);
    int wid  = g * NPG + nl;
    int lane = threadIdx.x & 63;
    int sub = lane >> 3;           // 0..7: edge j%8
    int cl  = lane & 7;            // 8-channel group (16 B)
    const unsigned short* hg = g16 + (size_t)g * NPG * 64;
    const float* dvg = dinv + g * NPG;
    float acc[8] = {};
    union U8 { uint4 u; __half2 h[4]; };
    int e0 = rowptr[wid], e1 = rowptr[wid + 1];
    int e = e0;
    for (; e + 16 <= e1; e += 16) {
        int s[2]; float dv[2]; U8 r[2];
        #pragma unroll
        for (int j = 0; j < 2; j++) s[j] = ssrc[e + 8 * j + sub];
        #pragma unroll
        for (int j = 0; j < 2; j++) dv[j] = dvg[s[j]];
        #pragma unroll
        for (int j = 0; j < 2; j++) r[j].u = *(const uint4*)&hg[(size_t)s[j] * 64 + cl * 8];
        #pragma unroll
        for (int j = 0; j < 2; j++) {
            #pragma unroll
            for (int k = 0; k < 4; k++) {
                float2 f = __half22float2(r[j].h[k]);
                acc[2 * k]     += dv[j] * f.x;
                acc[2 * k + 1] += dv[j] * f.y;
            }
        }
    }
    for (; e < e1; e += 8) {
        int ee = e + sub;
        int ss; float dv;
        if (ee < e1) { ss = ssrc[ee]; dv = dvg[ss]; }
        else         { ss = ssrc[e];  dv = 0.0f; }
        U8 r; r.u = *(const uint4*)&hg[(size_t)ss * 64 + cl * 8];
        #pragma unroll
        for (int k = 0; k < 4; k++) {
            float2 f = __half22float2(r.h[k]);
            acc[2 * k]     += dv * f.x;
            acc[2 * k + 1] += dv * f.y;
        }
    }
    #pragma unroll
    for (int k = 0; k < 8; k++) {
        acc[k] += __shfl_xor(acc[k], 8);
        acc[k] += __shfl_xor(acc[k], 16);
        acc[k] += __shfl_xor(acc[k], 32);
    }
    if (sub == 0) {
        float di = dvg[nl];
        float sw = 2.0f * di * di;
        U8 hv; hv.u = *(const uint4*)&hg[(size_t)nl * 64 + cl * 8];
        int cb = cl * 8;                     // 32%8==0: group fully in one branch
        float o[8];
        #pragma unroll
        for (int k = 0; k < 4; k++) {
            float2 f = __half22float2(hv.h[k]);
            o[2 * k]     = di * acc[2 * k]     + sw * f.x;
            o[2 * k + 1] = di * acc[2 * k + 1] + sw * f.y;
        }
        if (cb < 32) {
            #pragma unroll
            for (int k = 0; k < 8; k++) o[k] += ba2[cb + k];
        } else {
            #pragma unroll
            for (int k = 0; k < 8; k++) o[k] = fmaxf(o[k] + bx2[cb - 32 + k], 0.0f);
        }
        *(float4*)&s2[(size_t)wid * 64 + cb]     = make_float4(o[0], o[1], o[2], o[3]);
        *(float4*)&s2[(size_t)wid * 64 + cb + 4] = make_float4(o[4], o[5], o[6], o[7]);
    }
}

// ---------------- GEMM 2: g16 = fp16( [a1|x1] @ blockdiag(W_a2, W_x2) ) ----------------

__global__ __launch_bounds__(256) void k_gemm2(const float* __restrict__ Bm,
                                               const float* __restrict__ Wa2,
                                               const float* __restrict__ Wx2,
                                               unsigned short* __restrict__ g16) {
    __shared__ float xs[64][132];
    __shared__ float ws[64][68];
    int xcd = blockIdx.x & 7, slot = blockIdx.x >> 3;
    int g = xcd + 8 * (slot >> 4);
    int chunk = slot & 15;
    if (g >= NB) return;
    int row0 = g * NPG + chunk * 64;   // chunk 15 spills into next graph: benign dup
    int t = threadIdx.x;
    for (int i = 0; i < 4; i++) {
        int idx = t + 256 * i;
        int k = idx >> 4, c4 = idx & 15, c = c4 * 4;
        float4 v;
        if (c < 32) v = *(const float4*)&Wa2[k * 32 + c];
        else        v = *(const float4*)&Wx2[k * 32 + (c - 32)];
        *(float4*)&ws[k][c] = v;
    }
    for (int i = 0; i < 8; i++) {
        int idx = t + 256 * i;
        int r = idx >> 5, k4 = idx & 31;
        int rr = row0 + r; if (rr >= N_NODES) rr = N_NODES - 1;
        *(float4*)&xs[r][k4 * 4] = *(const float4*)&Bm[(size_t)rr * 128 + k4 * 4];
    }
    __syncthreads();
    int cg = t & 15, rg = t >> 4;
    int koff = (cg < 8) ? 0 : 64;
    float acc[4][4] = {};
    for (int k = 0; k < 64; k++) {
        float4 w = *(float4*)&ws[k][cg * 4];
        float xv[4];
        for (int i = 0; i < 4; i++) xv[i] = xs[rg * 4 + i][koff + k];
        for (int i = 0; i < 4; i++) {
            acc[i][0] += xv[i] * w.x; acc[i][1] += xv[i] * w.y;
            acc[i][2] += xv[i] * w.z; acc[i][3] += xv[i] * w.w;
        }
    }
    for (int i = 0; i < 4; i++) {
        int r = row0 + rg * 4 + i;
        if (r < N_NODES) {
            union { ushort4 u; __half2 h[2]; } pk;
            pk.h[0] = __floats2half2_rn(acc[i][0], acc[i][1]);
            pk.h[1] = __floats2half2_rn(acc[i][2], acc[i][3]);
            *(ushort4*)&g16[(size_t)r * 64 + cg * 4] = pk.u;
        }
    }
}

// ---------------- Segment softmax stats (cols 0..31), per graph ----------------

__global__ __launch_bounds__(256) void k_smax(const float* __restrict__ s2,
                                              float* __restrict__ gmax,
                                              float* __restrict__ sinv) {
    __shared__ float red[8][32];
    int g = (blockIdx.x & 7) + 8 * (blockIdx.x >> 3);
    if (g >= NB) return;
    int t = threadIdx.x;
    int c = t & 31, sub = t >> 5;
    size_t base = (size_t)g * NPG;
    float m = -1e30f;
    for (int n = sub; n < NPG; n += 8)
        m = fmaxf(m, s2[(base + n) * 64 + c]);
    red[sub][c] = m; __syncthreads();
    if (sub == 0) {
        for (int j = 1; j < 8; j++) m = fmaxf(m, red[j][c]);
        red[0][c] = m;
        gmax[g * 32 + c] = m;
    }
    __syncthreads();
    m = red[0][c];
    __syncthreads();
    float sum = 0.0f;
    for (int n = sub; n < NPG; n += 8)
        sum += expf(s2[(base + n) * 64 + c] - m);
    red[sub][c] = sum; __syncthreads();
    if (sub == 0) {
        for (int j = 1; j < 8; j++) sum += red[j][c];
        sinv[g * 32 + c] = 1.0f / sum;
    }
}

// ---------------- Bilinear pool (spill-free; exp at staging) ----------------

__global__ __launch_bounds__(256) void k_pool(const float* __restrict__ s2,
                                              const float* __restrict__ gmax,
                                              float* __restrict__ prods) {
    __shared__ float ta[50][32];
    __shared__ float tx[50][32];
    __shared__ float gm[32];
    int xcd = blockIdx.x & 7, slot = blockIdx.x >> 3;
    int g = xcd + 8 * (slot >> 2);
    int ch = slot & 3;
    if (g >= NB) return;
    int t = threadIdx.x;
    if (t < 32) gm[t] = gmax[g * 32 + t];
    int e  = t >> 3;
    int f4 = t & 7;
    float a0 = 0.f, a1 = 0.f, a2 = 0.f, a3 = 0.f;
    int base = g * NPG + ch * 250;
    for (int n0 = 0; n0 < 250; n0 += 50) {
        __syncthreads();
        for (int i = t; i < 50 * 16; i += 256) {
            int r = i >> 4, c4 = i & 15;
            float4 v = *(const float4*)&s2[(size_t)(base + n0 + r) * 64 + c4 * 4];
            if (c4 < 8) {
                int cb = c4 * 4;
                v.x = __expf(v.x - gm[cb + 0]);
                v.y = __expf(v.y - gm[cb + 1]);
                v.z = __expf(v.z - gm[cb + 2]);
                v.w = __expf(v.w - gm[cb + 3]);
                *(float4*)&ta[r][cb] = v;
            } else {
                *(float4*)&tx[r][(c4 - 8) * 4] = v;
            }
        }
        __syncthreads();
        #pragma unroll 5
        for (int n = 0; n < 50; n++) {
            float a   = ta[n][e];
            float4 xv = *(float4*)&tx[n][f4 * 4];
            a0 += a * xv.x; a1 += a * xv.y; a2 += a * xv.z; a3 += a * xv.w;
        }
    }
    *(float4*)&prods[((size_t)(g * 4 + ch)) * 1024 + e * 32 + f4 * 4] =
        make_float4(a0, a1, a2, a3);
}

// ---------------- Head: sum 4 chunk-partials, linear, softmax ----------------

__global__ __launch_bounds__(256) void k_head(const float* __restrict__ prods,
                                              const float* __restrict__ sinv,
                                              const float* __restrict__ Wlin,
                                              const float* __restrict__ blin,
                                              float* __restrict__ out) {
    __shared__ float red[4][NCLS];
    int g = (blockIdx.x & 7) + 8 * (blockIdx.x >> 3);
    if (g >= NB) return;
    int t = threadIdx.x;
    float p[NCLS];
    for (int c = 0; c < NCLS; c++) p[c] = 0.0f;
    const float* pg = &prods[(size_t)g * 4 * 1024];
    for (int j = 0; j < 4; j++) {
        int k = t * 4 + j;
        int e = k >> 5;
        float v = (pg[k] + pg[1024 + k] + pg[2048 + k] + pg[3072 + k]) * sinv[g * 32 + e];
        const float* wrow = &Wlin[(size_t)k * NCLS];
        for (int c = 0; c < NCLS; c++) p[c] += v * wrow[c];
    }
    for (int off = 32; off > 0; off >>= 1)
        for (int c = 0; c < NCLS; c++) p[c] += __shfl_down(p[c], off, 64);
    int wave = t >> 6, lane = t & 63;
    if (lane == 0)
        for (int c = 0; c < NCLS; c++) red[wave][c] = p[c];
    __syncthreads();
    if (t == 0) {
        float logits[NCLS]; float mx = -1e30f;
        for (int c = 0; c < NCLS; c++) {
            logits[c] = red[0][c] + red[1][c] + red[2][c] + red[3][c] + blin[c];
            mx = fmaxf(mx, logits[c]);
        }
        float s = 0.0f;
        for (int c = 0; c < NCLS; c++) { logits[c] = expf(logits[c] - mx); s += logits[c]; }
        float inv = 1.0f / s;
        for (int c = 0; c < NCLS; c++) out[g * NCLS + c] = logits[c] * inv;
    }
}

// ---------------- launch ----------------

extern "C" void kernel_launch(void* const* d_in, const int* in_sizes, int n_in,
                              void* d_out, int out_size, void* d_ws, size_t ws_size,
                              hipStream_t stream) {
    const float* x    = (const float*)d_in[0];
    const int*   ei   = (const int*)d_in[1];
    const float* Wa1  = (const float*)d_in[3];
    const float* ba1  = (const float*)d_in[4];
    const float* Wa2  = (const float*)d_in[5];
    const float* ba2  = (const float*)d_in[6];
    const float* Wx1  = (const float*)d_in[7];
    const float* bx1  = (const float*)d_in[8];
    const float* Wx2  = (const float*)d_in[9];
    const float* bx2  = (const float*)d_in[10];
    const float* Wlin = (const float*)d_in[11];
    const float* blin = (const float*)d_in[12];
    float* out = (float*)d_out;

    char* w = (char*)d_ws;
    auto alloc = [&](size_t bytes) -> void* {
        void* p = (void*)w;
        w += (bytes + 255) & ~(size_t)255;
        return p;
    };
    int*            rowptr = (int*)alloc((N_NODES + 1) * sizeof(int));
    float*          dinv   = (float*)alloc(N_NODES * sizeof(float));
    unsigned short* ssrc   = (unsigned short*)alloc((size_t)N_EDGES * sizeof(unsigned short));
    float*          gmax   = (float*)alloc(NB * DE * sizeof(float));
    float*          sinv   = (float*)alloc(NB * DE * sizeof(float));
    float*          prods  = (float*)alloc((size_t)NB * 4 * 1024 * sizeof(float));
    unsigned short* h16    = (unsigned short*)alloc((size_t)N_NODES * 128 * sizeof(unsigned short));
    unsigned short* g16    = (unsigned short*)alloc((size_t)N_NODES * 64 * sizeof(unsigned short));
    float*          bufB   = (float*)alloc((size_t)N_NODES * 128 * sizeof(float));
    float*          s2     = (float*)alloc((size_t)N_NODES * 64 * sizeof(float));

    const int* srcp = ei;
    const int* dstp = ei + N_EDGES;

    k_sort<<<8 * 13, 1024, 0, stream>>>(srcp, dstp, rowptr, dinv, ssrc);
    k_gemm1<<<8 * 13 * 32, 256, 0, stream>>>(x, Wa1, Wx1, h16);
    k_agg128<<<8 * 13 * 250, 256, 0, stream>>>(h16, rowptr, ssrc, dinv, ba1, bx1, bufB);
    k_gemm2<<<8 * 13 * 16, 256, 0, stream>>>(bufB, Wa2, Wx2, g16);
    k_agg64<<<8 * 13 * 250, 256, 0, stream>>>(g16, rowptr, ssrc, dinv, ba2, bx2, s2);
    k_smax<<<8 * 13, 256, 0, stream>>>(s2, gmax, sinv);
    k_pool<<<8 * 13 * 4, 256, 0, stream>>>(s2, gmax, prods);
    k_head<<<8 * 13, 256, 0, stream>>>(prods, sinv, Wlin, blin, out);
}